// Round 8
// baseline (535.004 us; speedup 1.0000x reference)
//
#include <hip/hip_runtime.h>

#define TOKENS  8192
#define HIDDEN  6144
#define EXPERTS 768
#define TOPK    12
#define RSF     2.5f
#define ROWH    (HIDDEN * 2)        // halves per W row, planar: [hi 6144 | lo 6144]

typedef float    f4 __attribute__((ext_vector_type(4)));
typedef _Float16 h8 __attribute__((ext_vector_type(8)));
typedef _Float16 h4 __attribute__((ext_vector_type(4)));
typedef _Float16 h2 __attribute__((ext_vector_type(2)));
typedef __fp16   g2 __attribute__((ext_vector_type(2)));

#define BM 128
#define BN 96
#define NKT 192                     // K-tiles of 32 floats
// LDS buffer (halves): A fp16 region 128 rows x 32 halves hi (4096) + lo (4096),
// then B region 96 rows x (32 hi + 32 lo) = 6144. Total 14336 halves = 28 KB.
#define AHALF 4096                  // halves: lo-plane offset within A region
#define AH    8192                  // halves: start of B region
#define BLO   3072                  // halves: lo plane offset within B region
#define BUFH  14336
#define LO_SCALE 4096.0f            // 2^12 keeps lo out of fp16-denormal range
#define LO_INV   2.44140625e-4f     // 2^-12

static __device__ inline h2 pk(float a, float b) {
    g2 r = __builtin_amdgcn_cvt_pkrtz(a, b);
    return __builtin_bit_cast(h2, r);
}

// 4 fp32 -> hi fp16x4 (RTZ) + lo fp16x4 ((x-hi)*2^12). Same per-element ops as
// the original cvt8 — bit-identical numerics.
static __device__ inline void cvt4(const f4 a, h4& hi, h4& lo) {
    h2 h01 = pk(a.x, a.y), h23 = pk(a.z, a.w);
    h2 l01 = pk((a.x - (float)h01[0]) * LO_SCALE, (a.y - (float)h01[1]) * LO_SCALE);
    h2 l23 = pk((a.z - (float)h23[0]) * LO_SCALE, (a.w - (float)h23[1]) * LO_SCALE);
    hi[0]=h01[0]; hi[1]=h01[1]; hi[2]=h23[0]; hi[3]=h23[1];
    lo[0]=l01[0]; lo[1]=l01[1]; lo[2]=l23[0]; lo[3]=l23[1];
}

// 8 fp32 -> hi/lo fp16x8 (W pre-pass)
static __device__ inline void cvt8(const f4 a, const f4 b, h8& hi, h8& lo) {
    h4 ha, la, hb, lb;
    cvt4(a, ha, la); cvt4(b, hb, lb);
    hi[0]=ha[0]; hi[1]=ha[1]; hi[2]=ha[2]; hi[3]=ha[3];
    hi[4]=hb[0]; hi[5]=hb[1]; hi[6]=hb[2]; hi[7]=hb[3];
    lo[0]=la[0]; lo[1]=la[1]; lo[2]=la[2]; lo[3]=la[3];
    lo[4]=lb[0]; lo[5]=lb[1]; lo[6]=lb[2]; lo[7]=lb[3];
}

// W only: one block per row, fp32 row -> planar [hi 6144h | lo 6144h].
// Reads whole row to regs, syncs, writes — alias-safe in-place or OOP.
__global__ __launch_bounds__(256)
void split_convert_w(const float* W, _Float16* WO) {
    const int row = blockIdx.x;
    const float* src = W + (size_t)row * HIDDEN;
    _Float16*   dst = WO + (size_t)row * ROWH;
    const int t = threadIdx.x;
    f4 a[3], b[3];
#pragma unroll
    for (int i = 0; i < 3; ++i) {
        const f4* p = (const f4*)(src + (size_t)(t + 256 * i) * 8);
        a[i] = p[0]; b[i] = p[1];
    }
    __syncthreads();
#pragma unroll
    for (int i = 0; i < 3; ++i) {
        h8 hi, lo;
        cvt8(a[i], b[i], hi, lo);
        const int g = t + 256 * i;
        *(h8*)(dst + (size_t)g * 8)          = hi;
        *(h8*)(dst + HIDDEN + (size_t)g * 8) = lo;
    }
}

typedef __attribute__((address_space(1))) const void av1;
typedef __attribute__((address_space(3))) void av3;
static __device__ inline void stage16(const void* g, void* l) {
    __builtin_amdgcn_global_load_lds((av1*)g, (av3*)l, 16, 0, 0);
}

// logits = X · Ws^T, split-fp16 MFMA, X-conversion fused into staging.
// R6 lesson: in-loop cvt on the READ path (per consuming wave) costs dup VALU
// + the fp32 A layout (128 B rows) bank-conflicts (1.26e7). Fix (T14 shape):
//  - A reg-staged: plain f4 global loads (same coalesced lane->(row,chunk) map
//    as gload_lds) issued at TOP of tile t for tile t+1; after the MFMA
//    cluster, cvt4 in-register (ONCE per element per block) + ds_write_b64
//    into the proven fp16 layout: 64 B rows, hi|lo planes, slot g^((r>>1)&3)
//    (geometry measured 0-conflict in R5).
//  - MFMA A-operands: single h8 ds_read each, no cvt after the barrier.
//  - B unchanged: pre-split fp16, gload_lds staging, same swizzle.
// Sync: R0-proven 2-barrier double-buffer; ds_writes go to buffer W while
// buffer R is read; __syncthreads (vmcnt+lgkm drain) publishes both.
// Grid (row-tile, col-tile): XCD = blockIdx.x % 8 -> X row-panel L2-local.
__global__ __launch_bounds__(256, 2)
void router_gemm(const float* __restrict__ X, const _Float16* __restrict__ Ws,
                 float* __restrict__ L) {
    __shared__ _Float16 sm[2 * BUFH];   // 57344 B, two buffers

    const int t    = threadIdx.x;
    const int bm   = blockIdx.x * BM;
    const int bn   = blockIdx.y * BN;
    const int lane = t & 63;
    const int w    = t >> 6;           // 0..3
    const int lr   = lane & 15;
    const int lq   = lane >> 4;        // 0..3 = k-group (8 floats each)

    // ---- A staging: 16 cells/tile (4/wave): global f4 + cvt + 2x ds_write_b64
    const float* psA[4];
    uint32_t     wofA[4];              // halves, buffer-relative (A hi plane)
#pragma unroll
    for (int q = 0; q < 4; ++q) {
        const int jA = w * 4 + q;              // 0..15
        const int r  = jA * 8 + (lane >> 3);   // 0..127
        const int c  = lane & 7;               // fp32 chunk (4 floats)
        psA[q]  = X + (size_t)(bm + r) * HIDDEN + c * 4;
        wofA[q] = (uint32_t)(r * 32 + (((c >> 1) ^ ((r >> 1) & 3)) * 8) + (c & 1) * 4);
    }

    // ---- B staging: 12 gload_lds per tile, 3 per wave (pre-split fp16)
    const _Float16* psB[3];
    uint32_t        ldsoB[3];
#pragma unroll
    for (int q = 0; q < 3; ++q) {
        const int j    = w * 3 + q;            // 0..11
        const int isLo = (j >= 6);
        const int jj   = isLo ? j - 6 : j;     // 0..5
        const int r    = jj * 16 + (lane >> 2);    // 0..95
        const int p    = lane & 3;
        const int g    = p ^ ((r >> 1) & 3);   // source k-slot for this dest slot
        psB[q]   = Ws + (size_t)(bn + r) * ROWH + g * 8 + isLo * HIDDEN;
        ldsoB[q] = (uint32_t)(AH + isLo * BLO + jj * 512);
    }

    // ---- A fragment LDS offsets (halves): row r, k-group lq, proven XOR map
    uint32_t aoff[4];
#pragma unroll
    for (int mi = 0; mi < 4; ++mi) {
        const int r = (w & 1) * 64 + mi * 16 + lr;
        aoff[mi] = (uint32_t)(r * 32 + ((lq ^ ((r >> 1) & 3)) * 8));
    }
    // ---- B fragment LDS offsets
    uint32_t boff[3];
#pragma unroll
    for (int ni = 0; ni < 3; ++ni) {
        const int r = (w >> 1) * 48 + ni * 16 + lr;   // 0..95 local
        boff[ni] = (uint32_t)(AH + r * 32 + ((lq ^ ((r >> 1) & 3)) * 8));
    }

    f4 acc_h[4][3], acc_c[4][3];
#pragma unroll
    for (int i = 0; i < 4; ++i)
#pragma unroll
        for (int j = 0; j < 3; ++j) { acc_h[i][j] = f4{0,0,0,0}; acc_c[i][j] = f4{0,0,0,0}; }

    // ---- prologue: tile 0 -> buffer 0 (A: load+cvt+write now; B: gload_lds)
#pragma unroll
    for (int q = 0; q < 4; ++q) {
        f4 av = *(const f4*)psA[q]; psA[q] += 32;
        h4 hi, lo; cvt4(av, hi, lo);
        *(h4*)(sm + wofA[q])         = hi;
        *(h4*)(sm + wofA[q] + AHALF) = lo;
    }
#pragma unroll
    for (int q = 0; q < 3; ++q) { stage16((const void*)psB[q], (void*)(sm + ldsoB[q])); psB[q] += 32; }

    auto do_tile = [&](const uint32_t boR, const uint32_t boW, const bool doStage) {
        f4 av[4];
        if (doStage) {
#pragma unroll
            for (int q = 0; q < 4; ++q) { av[q] = *(const f4*)psA[q]; psA[q] += 32; }
#pragma unroll
            for (int q = 0; q < 3; ++q) { stage16((const void*)psB[q], (void*)(sm + boW + ldsoB[q])); psB[q] += 32; }
        }
        h8 ah[4], al[4], bh[3], bl[3];
#pragma unroll
        for (int mi = 0; mi < 4; ++mi) {
            ah[mi] = *(const h8*)(sm + boR + aoff[mi]);
            al[mi] = *(const h8*)(sm + boR + aoff[mi] + AHALF);
        }
#pragma unroll
        for (int ni = 0; ni < 3; ++ni) {
            bh[ni] = *(const h8*)(sm + boR + boff[ni]);
            bl[ni] = *(const h8*)(sm + boR + boff[ni] + BLO);
        }
#pragma unroll
        for (int mi = 0; mi < 4; ++mi)
#pragma unroll
            for (int ni = 0; ni < 3; ++ni) {
                acc_h[mi][ni] = __builtin_amdgcn_mfma_f32_16x16x32_f16(ah[mi], bh[ni], acc_h[mi][ni], 0, 0, 0);
                acc_c[mi][ni] = __builtin_amdgcn_mfma_f32_16x16x32_f16(ah[mi], bl[ni], acc_c[mi][ni], 0, 0, 0);
                acc_c[mi][ni] = __builtin_amdgcn_mfma_f32_16x16x32_f16(al[mi], bh[ni], acc_c[mi][ni], 0, 0, 0);
            }
        if (doStage) {
            // cvt + publish A(t+1) after the MFMA wall (loads had full cover)
#pragma unroll
            for (int q = 0; q < 4; ++q) {
                h4 hi, lo; cvt4(av[q], hi, lo);
                *(h4*)(sm + boW + wofA[q])         = hi;
                *(h4*)(sm + boW + wofA[q] + AHALF) = lo;
            }
        }
    };

    for (int T2 = 0; T2 < NKT / 2; ++T2) {
        __syncthreads();                       // tile 2T staged; prev buf1 reads done
        do_tile(0u, (uint32_t)BUFH, true);     // read buf0, stage 2T+1 -> buf1
        __syncthreads();                       // tile 2T+1 staged; buf0 reads done
        do_tile((uint32_t)BUFH, 0u, T2 != NKT / 2 - 1);  // read buf1, stage 2T+2 -> buf0
    }

    // C/D layout: col = lane&15, row = (lane>>4)*4 + reg
#pragma unroll
    for (int mi = 0; mi < 4; ++mi)
#pragma unroll
        for (int ni = 0; ni < 3; ++ni)
#pragma unroll
            for (int r = 0; r < 4; ++r) {
                const int gm = bm + (w & 1) * 64 + mi * 16 + lq * 4 + r;
                const int gn = bn + (w >> 1) * 48 + ni * 16 + lr;
                L[(size_t)gm * EXPERTS + gn] = acc_h[mi][ni][r] + acc_c[mi][ni][r] * LO_INV;
            }
}

// One wave per token: softmax over 768, bias-corrected top-12 (desc, ties -> lower idx).
__global__ __launch_bounds__(256)
void router_topk(const float* __restrict__ L, const float* __restrict__ bias,
                 float* __restrict__ outIdx, float* __restrict__ outW) {
    __shared__ float sb[EXPERTS];
    const int t = threadIdx.x;
    for (int i = t; i < EXPERTS; i += 256) sb[i] = bias[i];
    __syncthreads();

    const int lane  = t & 63;
    const int wave  = t >> 6;
    const int token = blockIdx.x * 4 + wave;
    const float* row = L + (size_t)token * EXPERTS;

    float lg[12];
#pragma unroll
    for (int j = 0; j < 12; ++j) lg[j] = row[lane + 64 * j];

    float m = lg[0];
#pragma unroll
    for (int j = 1; j < 12; ++j) m = fmaxf(m, lg[j]);
#pragma unroll
    for (int o = 32; o > 0; o >>= 1) m = fmaxf(m, __shfl_xor(m, o));

    float s = 0.0f;
#pragma unroll
    for (int j = 0; j < 12; ++j) { lg[j] = __expf(lg[j] - m); s += lg[j]; }
#pragma unroll
    for (int o = 32; o > 0; o >>= 1) s += __shfl_xor(s, o);
    const float inv = 1.0f / s;

    float cand[12];
#pragma unroll
    for (int j = 0; j < 12; ++j) {
        lg[j] *= inv;
        cand[j] = lg[j] + sb[lane + 64 * j];
    }

#pragma unroll
    for (int r = 0; r < TOPK; ++r) {
        float bv = -__builtin_inff();
        int   bi = EXPERTS;
#pragma unroll
        for (int j = 0; j < 12; ++j) {
            const int e = lane + 64 * j;
            const bool better = (cand[j] > bv) || (cand[j] == bv && e < bi);
            bv = better ? cand[j] : bv;
            bi = better ? e : bi;
        }
#pragma unroll
        for (int o = 32; o > 0; o >>= 1) {
            const float ov = __shfl_xor(bv, o);
            const int   oi = __shfl_xor(bi, o);
            const bool better = (ov > bv) || (ov == bv && oi < bi);
            bv = better ? ov : bv;
            bi = better ? oi : bi;
        }
        if (lane == 0) {
            outIdx[token * TOPK + r] = (float)bi;
            outW  [token * TOPK + r] = (bv - sb[bi]) * RSF;
        }
        if ((bi & 63) == lane) {
            const int slot = bi >> 6;
#pragma unroll
            for (int j = 0; j < 12; ++j)
                if (j == slot) cand[j] = -__builtin_inff();
        }
    }
}

extern "C" void kernel_launch(void* const* d_in, const int* in_sizes, int n_in,
                              void* d_out, int out_size, void* d_ws, size_t ws_size,
                              hipStream_t stream) {
    float* X = (float*)d_in[0];   // [8192, 6144] fp32 — read-only
    float* W = (float*)d_in[1];   // [768, 6144]  fp32
    const float* B = (const float*)d_in[2];

    const size_t bytesW = (size_t)EXPERTS * HIDDEN * sizeof(float);  // 18.9 MB
    const size_t bytesL = (size_t)TOKENS * EXPERTS * sizeof(float);  // 25.2 MB

    // W split out-of-place into workspace when it fits (inputs pristine);
    // else in-place (row-self-contained conversion is alias-safe).
    _Float16* Ws; float* logits;
    if (ws_size >= bytesW + bytesL) {
        char* p = (char*)d_ws;
        Ws     = (_Float16*)p;
        logits = (float*)(p + bytesW);
    } else {
        Ws     = (_Float16*)W;
        logits = (float*)d_ws;
    }

    float* outIdx = (float*)d_out;            // indices as float values
    float* outW   = outIdx + (size_t)TOKENS * TOPK;

    split_convert_w<<<EXPERTS, 256, 0, stream>>>(W, Ws);

    dim3 grid_gemm(TOKENS / BM, EXPERTS / BN);                // (64, 8): XCD-local
    router_gemm<<<grid_gemm, 256, 0, stream>>>((const float*)X, (const _Float16*)Ws, logits);
    router_topk<<<TOKENS / 4, 256, 0, stream>>>(logits, B, outIdx, outW);
}

// Round 10
// 492.770 us; speedup vs baseline: 1.0857x; 1.0857x over previous
//
#include <hip/hip_runtime.h>

#define TOKENS  8192
#define HIDDEN  6144
#define EXPERTS 768
#define TOPK    12
#define RSF     2.5f
#define ROWH    (HIDDEN * 2)        // halves per W row, planar: [hi 6144 | lo 6144]

typedef float    f4 __attribute__((ext_vector_type(4)));
typedef _Float16 h8 __attribute__((ext_vector_type(8)));
typedef _Float16 h4 __attribute__((ext_vector_type(4)));
typedef _Float16 h2 __attribute__((ext_vector_type(2)));
typedef __fp16   g2 __attribute__((ext_vector_type(2)));

#define BM 128
#define BN 96
#define NKT 192                     // K-tiles of 32 floats
// LDS buffer (halves): A fp32 region 128 rows x 128 B = 8192, then B split-fp16
// region 96 rows x (32 hi + 32 lo) = 6144.  Total 14336 halves = 28672 B.
#define AH   8192                   // halves: start of B region
#define BLO  3072                   // halves: lo plane offset within B region
#define BUFH 14336
#define LO_SCALE 4096.0f            // 2^12 keeps lo out of fp16-denormal range
#define LO_INV   2.44140625e-4f     // 2^-12

static __device__ inline h2 pk(float a, float b) {
    g2 r = __builtin_amdgcn_cvt_pkrtz(a, b);
    return __builtin_bit_cast(h2, r);
}

// 8 fp32 -> hi fp16x8 (RTZ) + lo fp16x8 ((x-hi)*2^12)
static __device__ inline void cvt8(const f4 a, const f4 b, h8& hi, h8& lo) {
    h2 ha = pk(a.x, a.y), hb = pk(a.z, a.w), hc = pk(b.x, b.y), hd = pk(b.z, b.w);
    h2 la = pk((a.x - (float)ha[0]) * LO_SCALE, (a.y - (float)ha[1]) * LO_SCALE);
    h2 lb = pk((a.z - (float)hb[0]) * LO_SCALE, (a.w - (float)hb[1]) * LO_SCALE);
    h2 lc = pk((b.x - (float)hc[0]) * LO_SCALE, (b.y - (float)hc[1]) * LO_SCALE);
    h2 ld = pk((b.z - (float)hd[0]) * LO_SCALE, (b.w - (float)hd[1]) * LO_SCALE);
    hi[0]=ha[0]; hi[1]=ha[1]; hi[2]=hb[0]; hi[3]=hb[1];
    hi[4]=hc[0]; hi[5]=hc[1]; hi[6]=hd[0]; hi[7]=hd[1];
    lo[0]=la[0]; lo[1]=la[1]; lo[2]=lb[0]; lo[3]=lb[1];
    lo[4]=lc[0]; lo[5]=lc[1]; lo[6]=ld[0]; lo[7]=ld[1];
}

// W only: one block per row, fp32 row -> planar [hi 6144h | lo 6144h].
// Reads whole row to regs, syncs, writes — alias-safe in-place or OOP.
__global__ __launch_bounds__(256)
void split_convert_w(const float* W, _Float16* WO) {
    const int row = blockIdx.x;
    const float* src = W + (size_t)row * HIDDEN;
    _Float16*   dst = WO + (size_t)row * ROWH;
    const int t = threadIdx.x;
    f4 a[3], b[3];
#pragma unroll
    for (int i = 0; i < 3; ++i) {
        const f4* p = (const f4*)(src + (size_t)(t + 256 * i) * 8);
        a[i] = p[0]; b[i] = p[1];
    }
    __syncthreads();
#pragma unroll
    for (int i = 0; i < 3; ++i) {
        h8 hi, lo;
        cvt8(a[i], b[i], hi, lo);
        const int g = t + 256 * i;
        *(h8*)(dst + (size_t)g * 8)          = hi;
        *(h8*)(dst + HIDDEN + (size_t)g * 8) = lo;
    }
}

typedef __attribute__((address_space(1))) const void av1;
typedef __attribute__((address_space(3))) void av3;
static __device__ inline void stage16(const void* g, void* l) {
    __builtin_amdgcn_global_load_lds((av1*)g, (av3*)l, 16, 0, 0);
}

// logits = X · Ws^T, split-fp16 MFMA, X-conversion fused (R6 structure, proven
// correct @ 285us). R9's cross-phase reg pipeline failed correctness ->
// abandoned. This round: R6 verbatim EXCEPT the wave->output remap (4x1 over
// MxN instead of 2x2): wave w owns A rows [32w,32w+32) and ALL 96 B cols.
// Each A row is read+cvt'd by exactly ONE wave (R6 duplicated both across
// wave pairs): cvt VALU halves, A b128 reads halve (conflict source), B reads
// grow 6->12 (conflict-free region). Staging maps, LDS layout, barriers,
// numerics: byte-identical to R6.
// Grid (row-tile, col-tile): XCD = blockIdx.x % 8 -> X row-panel L2-local.
__global__ __launch_bounds__(256, 2)
void router_gemm(const float* __restrict__ X, const _Float16* __restrict__ Ws,
                 float* __restrict__ L) {
    __shared__ _Float16 sm[2 * BUFH];   // 57344 B, two buffers

    const int t    = threadIdx.x;
    const int bm   = blockIdx.x * BM;
    const int bn   = blockIdx.y * BN;
    const int lane = t & 63;
    const int w    = t >> 6;           // 0..3
    const int lr   = lane & 15;
    const int lq   = lane >> 4;        // 0..3 = k-group (8 floats each)

    // ---- A staging: 16 gload_lds per tile, 4 per wave (fp32, pre-swizzled src)
    const float* psA[4];
    uint32_t     ldsoA[4];             // halves, buffer-relative (wave-uniform)
#pragma unroll
    for (int q = 0; q < 4; ++q) {
        const int jA = w * 4 + q;              // 0..15
        const int r  = jA * 8 + (lane >> 3);   // 0..127
        const int p  = lane & 7;               // dest 16B-chunk (linear in lane)
        const int c  = p ^ (r & 7);            // source 16B-chunk
        psA[q]   = X + (size_t)(bm + r) * HIDDEN + c * 4;
        ldsoA[q] = (uint32_t)(jA * 512);
    }

    // ---- B staging: 12 gload_lds per tile, 3 per wave (pre-split fp16)
    const _Float16* psB[3];
    uint32_t        ldsoB[3];
#pragma unroll
    for (int q = 0; q < 3; ++q) {
        const int j    = w * 3 + q;            // 0..11
        const int isLo = (j >= 6);
        const int jj   = isLo ? j - 6 : j;     // 0..5
        const int r    = jj * 16 + (lane >> 2);    // 0..95
        const int p    = lane & 3;
        const int g    = p ^ ((r >> 1) & 3);   // source k-slot for this dest slot
        psB[q]   = Ws + (size_t)(bn + r) * ROWH + g * 8 + isLo * HIDDEN;
        ldsoB[q] = (uint32_t)(AH + isLo * BLO + jj * 512);
    }

    // ---- A fragment LDS offsets (halves): wave w owns rows [32w, 32w+32)
    // chunk0 = (2lq)^(r&7) at byte r*128 + chunk0*16; chunk1 = chunk0^1 -> ^8 halves.
    uint32_t aoff[2];
#pragma unroll
    for (int mi = 0; mi < 2; ++mi) {
        const int r = w * 32 + mi * 16 + lr;
        aoff[mi] = r * 64 + (uint32_t)(((2 * lq) ^ (r & 7)) * 8);
    }
    // ---- B fragment LDS offsets: every wave reads all 96 B rows
    uint32_t boff[6];
#pragma unroll
    for (int ni = 0; ni < 6; ++ni) {
        const int r = ni * 16 + lr;            // 0..95 local
        boff[ni] = (uint32_t)(AH + r * 32 + ((lq ^ ((r >> 1) & 3)) * 8));
    }

    f4 acc_h[2][6], acc_c[2][6];
#pragma unroll
    for (int i = 0; i < 2; ++i)
#pragma unroll
        for (int j = 0; j < 6; ++j) { acc_h[i][j] = f4{0,0,0,0}; acc_c[i][j] = f4{0,0,0,0}; }

    // prologue: stage tile 0 into buffer 0
#pragma unroll
    for (int q = 0; q < 4; ++q) { stage16((const void*)psA[q], (void*)(sm + ldsoA[q])); psA[q] += 32; }
#pragma unroll
    for (int q = 0; q < 3; ++q) { stage16((const void*)psB[q], (void*)(sm + ldsoB[q])); psB[q] += 32; }

    auto do_tile = [&](const uint32_t boR, const uint32_t boW, const bool doStage) {
        if (doStage) {
#pragma unroll
            for (int q = 0; q < 4; ++q) { stage16((const void*)psA[q], (void*)(sm + boW + ldsoA[q])); psA[q] += 32; }
#pragma unroll
            for (int q = 0; q < 3; ++q) { stage16((const void*)psB[q], (void*)(sm + boW + ldsoB[q])); psB[q] += 32; }
        }
        // A: read fp32, split in-register (identical arithmetic to W pre-pass);
        // each A fragment converted by exactly one wave now.
        h8 ah[2], al[2], bh[6], bl[6];
#pragma unroll
        for (int mi = 0; mi < 2; ++mi) {
            const uint32_t ao = boR + aoff[mi];
            const f4 va = *(const f4*)(sm + ao);
            const f4 vb = *(const f4*)(sm + (ao ^ 8u));
            cvt8(va, vb, ah[mi], al[mi]);
        }
#pragma unroll
        for (int ni = 0; ni < 6; ++ni) {
            bh[ni] = *(const h8*)(sm + boR + boff[ni]);
            bl[ni] = *(const h8*)(sm + boR + boff[ni] + BLO);
        }
#pragma unroll
        for (int mi = 0; mi < 2; ++mi)
#pragma unroll
            for (int ni = 0; ni < 6; ++ni) {
                acc_h[mi][ni] = __builtin_amdgcn_mfma_f32_16x16x32_f16(ah[mi], bh[ni], acc_h[mi][ni], 0, 0, 0);
                acc_c[mi][ni] = __builtin_amdgcn_mfma_f32_16x16x32_f16(ah[mi], bl[ni], acc_c[mi][ni], 0, 0, 0);
                acc_c[mi][ni] = __builtin_amdgcn_mfma_f32_16x16x32_f16(al[mi], bh[ni], acc_c[mi][ni], 0, 0, 0);
            }
    };

    for (int T2 = 0; T2 < NKT / 2; ++T2) {
        __syncthreads();                       // tile 2T staged; prev buf1 reads done
        do_tile(0u, (uint32_t)BUFH, true);     // read buf0, stage 2T+1 -> buf1
        __syncthreads();                       // tile 2T+1 staged; buf0 reads done
        do_tile((uint32_t)BUFH, 0u, T2 != NKT / 2 - 1);  // read buf1, stage 2T+2 -> buf0
    }

    // C/D layout: col = lane&15, row = (lane>>4)*4 + reg
#pragma unroll
    for (int mi = 0; mi < 2; ++mi)
#pragma unroll
        for (int ni = 0; ni < 6; ++ni)
#pragma unroll
            for (int r = 0; r < 4; ++r) {
                const int gm = bm + w * 32 + mi * 16 + lq * 4 + r;
                const int gn = bn + ni * 16 + lr;
                L[(size_t)gm * EXPERTS + gn] = acc_h[mi][ni][r] + acc_c[mi][ni][r] * LO_INV;
            }
}

// One wave per token: softmax over 768, bias-corrected top-12 (desc, ties -> lower idx).
__global__ __launch_bounds__(256)
void router_topk(const float* __restrict__ L, const float* __restrict__ bias,
                 float* __restrict__ outIdx, float* __restrict__ outW) {
    __shared__ float sb[EXPERTS];
    const int t = threadIdx.x;
    for (int i = t; i < EXPERTS; i += 256) sb[i] = bias[i];
    __syncthreads();

    const int lane  = t & 63;
    const int wave  = t >> 6;
    const int token = blockIdx.x * 4 + wave;
    const float* row = L + (size_t)token * EXPERTS;

    float lg[12];
#pragma unroll
    for (int j = 0; j < 12; ++j) lg[j] = row[lane + 64 * j];

    float m = lg[0];
#pragma unroll
    for (int j = 1; j < 12; ++j) m = fmaxf(m, lg[j]);
#pragma unroll
    for (int o = 32; o > 0; o >>= 1) m = fmaxf(m, __shfl_xor(m, o));

    float s = 0.0f;
#pragma unroll
    for (int j = 0; j < 12; ++j) { lg[j] = __expf(lg[j] - m); s += lg[j]; }
#pragma unroll
    for (int o = 32; o > 0; o >>= 1) s += __shfl_xor(s, o);
    const float inv = 1.0f / s;

    float cand[12];
#pragma unroll
    for (int j = 0; j < 12; ++j) {
        lg[j] *= inv;
        cand[j] = lg[j] + sb[lane + 64 * j];
    }

#pragma unroll
    for (int r = 0; r < TOPK; ++r) {
        float bv = -__builtin_inff();
        int   bi = EXPERTS;
#pragma unroll
        for (int j = 0; j < 12; ++j) {
            const int e = lane + 64 * j;
            const bool better = (cand[j] > bv) || (cand[j] == bv && e < bi);
            bv = better ? cand[j] : bv;
            bi = better ? e : bi;
        }
#pragma unroll
        for (int o = 32; o > 0; o >>= 1) {
            const float ov = __shfl_xor(bv, o);
            const int   oi = __shfl_xor(bi, o);
            const bool better = (ov > bv) || (ov == bv && oi < bi);
            bv = better ? ov : bv;
            bi = better ? oi : bi;
        }
        if (lane == 0) {
            outIdx[token * TOPK + r] = (float)bi;
            outW  [token * TOPK + r] = (bv - sb[bi]) * RSF;
        }
        if ((bi & 63) == lane) {
            const int slot = bi >> 6;
#pragma unroll
            for (int j = 0; j < 12; ++j)
                if (j == slot) cand[j] = -__builtin_inff();
        }
    }
}

extern "C" void kernel_launch(void* const* d_in, const int* in_sizes, int n_in,
                              void* d_out, int out_size, void* d_ws, size_t ws_size,
                              hipStream_t stream) {
    float* X = (float*)d_in[0];   // [8192, 6144] fp32 — read-only
    float* W = (float*)d_in[1];   // [768, 6144]  fp32
    const float* B = (const float*)d_in[2];

    const size_t bytesW = (size_t)EXPERTS * HIDDEN * sizeof(float);  // 18.9 MB
    const size_t bytesL = (size_t)TOKENS * EXPERTS * sizeof(float);  // 25.2 MB

    // W split out-of-place into workspace when it fits (inputs pristine);
    // else in-place (row-self-contained conversion is alias-safe).
    _Float16* Ws; float* logits;
    if (ws_size >= bytesW + bytesL) {
        char* p = (char*)d_ws;
        Ws     = (_Float16*)p;
        logits = (float*)(p + bytesW);
    } else {
        Ws     = (_Float16*)W;
        logits = (float*)d_ws;
    }

    float* outIdx = (float*)d_out;            // indices as float values
    float* outW   = outIdx + (size_t)TOKENS * TOPK;

    split_convert_w<<<EXPERTS, 256, 0, stream>>>(W, Ws);

    dim3 grid_gemm(TOKENS / BM, EXPERTS / BN);                // (64, 8): XCD-local
    router_gemm<<<grid_gemm, 256, 0, stream>>>((const float*)X, (const _Float16*)Ws, logits);
    router_topk<<<TOKENS / 4, 256, 0, stream>>>(logits, B, outIdx, outW);
}